// Round 23
// baseline (119.219 us; speedup 1.0000x reference)
//
#include <hip/hip_runtime.h>
#include <hip/hip_bf16.h>

// CausalAttention MI355X: B=2 L=2048 D=1024 H=16 HD=64
// prep (fused converts) -> QKV GEMM (128x128, 3 blocks/CU staggered,
// XCD swizzle, V^T direct epilogue) -> flash attention (q-split 64-row
// blocks, KVBLK=64, 4 blocks/CU, serial reductions [R19-exact]) ->
// out GEMM (64x64, 4/CU).

using bf16x8 = __attribute__((ext_vector_type(8))) short;
using f32x4  = __attribute__((ext_vector_type(4))) float;

static __device__ __forceinline__ unsigned short f2b(float f) {
  unsigned u = __builtin_bit_cast(unsigned, f);
  unsigned r = (u + 0x7fffu + ((u >> 16) & 1u)) >> 16;
  return (unsigned short)r;
}

// pack 2 f32 -> 2 bf16 in one instr (no builtin on gfx950; T12 recipe)
static __device__ __forceinline__ unsigned cvtpk(float lo, float hi) {
  unsigned r;
  asm("v_cvt_pk_bf16_f32 %0, %1, %2" : "=v"(r) : "v"(lo), "v"(hi));
  return r;
}

// async global->LDS, 16B/lane; LDS dest wave-uniform (HW adds lane*16),
// per-lane row/swizzle on the GLOBAL address (rule 21 / m173).
static __device__ __forceinline__ void gl_lds16(const void* g, void* l) {
  __builtin_amdgcn_global_load_lds(
      (const __attribute__((address_space(1))) unsigned int*)g,
      (__attribute__((address_space(3))) unsigned int*)l, 16, 0, 0);
}

// ----------------------------------------------------- fused input prep
__global__ __launch_bounds__(256) void prep_inputs(
    const float* __restrict__ x, const float* __restrict__ w_qkv,
    const float* __restrict__ w_out, unsigned short* __restrict__ xb,
    unsigned short* __restrict__ wqkvt, unsigned short* __restrict__ woutt) {
  const int bid = blockIdx.x, t = threadIdx.x;
  if (bid < 2048) {
    int i = bid * 256 + t;
    const float4* p = reinterpret_cast<const float4*>(x) + (size_t)i * 2;
    float4 a = p[0], b = p[1];
    bf16x8 o;
    o[0] = f2b(a.x); o[1] = f2b(a.y); o[2] = f2b(a.z); o[3] = f2b(a.w);
    o[4] = f2b(b.x); o[5] = f2b(b.y); o[6] = f2b(b.z); o[7] = f2b(b.w);
    reinterpret_cast<bf16x8*>(xb)[i] = o;
  } else if (bid < 3584) {
    int idx = (bid - 2048) * 256 + t;            // N=3072, K=1024
    int n = idx % 3072, k0 = (idx / 3072) * 8;
    if (k0 < 1024) {
      bf16x8 o;
#pragma unroll
      for (int j = 0; j < 8; ++j) o[j] = f2b(w_qkv[(size_t)(k0 + j) * 3072 + n]);
      *reinterpret_cast<bf16x8*>(&wqkvt[(size_t)n * 1024 + k0]) = o;
    }
  } else {
    int idx = (bid - 3584) * 256 + t;            // N=1024, K=1024
    int n = idx % 1024, k0 = (idx / 1024) * 8;
    if (k0 < 1024) {
      bf16x8 o;
#pragma unroll
      for (int j = 0; j < 8; ++j) o[j] = f2b(w_out[(size_t)(k0 + j) * 1024 + n]);
      *reinterpret_cast<bf16x8*>(&woutt[(size_t)n * 1024 + k0]) = o;
    }
  }
}

// ------------------------------------------------ QKV GEMM: 128x128, stagger
// grid (24,32) = 768 blocks = exactly 3/CU (even balance + 3 staggered
// streams; fixes the 1.5/CU imbalance of the 256x128 tiling). R7-verified
// frag math; R10 stagger + bijective XCD swizzle (96 blocks/XCD); R20
// vectorized epilogue with direct V^T store.
__global__ __launch_bounds__(256) void gemm_qkv(
    const unsigned short* __restrict__ A,
    const unsigned short* __restrict__ Bt,
    const float* __restrict__ bias,
    unsigned short* __restrict__ qb, unsigned short* __restrict__ kb,
    unsigned short* __restrict__ vt) {
  __shared__ __align__(16) unsigned short lA[128 * 64];
  __shared__ __align__(16) unsigned short lB[128 * 64];
  const int t = threadIdx.x;
  const int lin = blockIdx.y * 24 + blockIdx.x;          // grid (24,32)
  const int nb  = (lin & 7) * 96 + (lin >> 3);           // bijective, 96/XCD
  const int bm = nb / 24, bn = nb % 24;
  const int s0 = (nb * 5) & 15;
  const int w = t >> 6, lane = t & 63;
  const int lr = lane & 15, lg = lane >> 4;
  const int wm = (w >> 1) * 64, wn = (w & 1) * 64;
  const int g8  = lane >> 3;
  const int swz = ((lane & 7) * 16) ^ (g8 << 4);

  f32x4 acc[4][4];
#pragma unroll
  for (int i = 0; i < 4; ++i)
#pragma unroll
    for (int j = 0; j < 4; ++j) acc[i][j] = f32x4{0.f, 0.f, 0.f, 0.f};

  const size_t am = (size_t)bm * 128, bnr = (size_t)bn * 128;

  for (int kt = 0; kt < 16; ++kt) {
    const int k0 = ((kt + s0) & 15) * 64;
#pragma unroll
    for (int i = 0; i < 4; ++i) {
      const int rs = i * 32 + w * 8;               // uniform strip base
      gl_lds16((const char*)(A + (am + rs + g8) * 1024 + k0) + swz,
               (char*)lA + rs * 128);
      gl_lds16((const char*)(Bt + (bnr + rs + g8) * 1024 + k0) + swz,
               (char*)lB + rs * 128);
    }
    __syncthreads();
#pragma unroll
    for (int kk = 0; kk < 64; kk += 32) {
      bf16x8 af[4], bfr[4];
#pragma unroll
      for (int fm = 0; fm < 4; ++fm) {
        int row = wm + fm * 16 + lr;
        af[fm] = *reinterpret_cast<const bf16x8*>(
            (const char*)lA + row * 128 + ((2 * kk + lg * 16) ^ ((lr & 7) << 4)));
      }
#pragma unroll
      for (int fn = 0; fn < 4; ++fn) {
        int row = wn + fn * 16 + lr;
        bfr[fn] = *reinterpret_cast<const bf16x8*>(
            (const char*)lB + row * 128 + ((2 * kk + lg * 16) ^ ((lr & 7) << 4)));
      }
#pragma unroll
      for (int fm = 0; fm < 4; ++fm)
#pragma unroll
        for (int fn = 0; fn < 4; ++fn)
          acc[fm][fn] = __builtin_amdgcn_mfma_f32_16x16x32_bf16(
              af[fm], bfr[fn], acc[fm][fn], 0, 0, 0);
    }
    __syncthreads();
  }

#pragma unroll
  for (int fm = 0; fm < 4; ++fm) {
#pragma unroll
    for (int fn = 0; fn < 4; ++fn) {
      const int row0 = bm * 128 + wm + fm * 16 + lg * 4;
      const int col  = bn * 128 + wn + fn * 16 + lr;
      const float bc = bias[col];
      float v4[4];
#pragma unroll
      for (int r = 0; r < 4; ++r) v4[r] = acc[fm][fn][r] + bc;
      const int bb = row0 >> 11, l0 = row0 & 2047;
      const int which = col >> 10, hn = col & 1023;
      const int h = hn >> 6, d = hn & 63;
      const int bh = bb * 16 + h;
      if (which == 0) {
#pragma unroll
        for (int r = 0; r < 4; ++r)
          qb[((size_t)bh * 2048 + l0 + r) * 64 + d] = f2b(v4[r] * 0.180336879f);
      } else if (which == 1) {
#pragma unroll
        for (int r = 0; r < 4; ++r)
          kb[((size_t)bh * 2048 + l0 + r) * 64 + d] = f2b(v4[r]);
      } else {
        ushort4 o;
        o.x = f2b(v4[0]); o.y = f2b(v4[1]); o.z = f2b(v4[2]); o.w = f2b(v4[3]);
        *reinterpret_cast<ushort4*>(&vt[((size_t)bh * 64 + d) * 2048 + l0]) = o;
      }
    }
  }
}

// ---------------------------------------------------------------- out GEMM
// (R22 verified: 64x64 tile, 4 blocks/CU, stagger + XCD swizzle)
__global__ __launch_bounds__(256) void gemm_out(
    const unsigned short* __restrict__ A,
    const unsigned short* __restrict__ Bt,
    const float* __restrict__ bias, float* __restrict__ outf) {
  __shared__ __align__(16) unsigned short lA[64 * 64];
  __shared__ __align__(16) unsigned short lB[64 * 64];
  const int t = threadIdx.x;
  const int lin = blockIdx.y * 16 + blockIdx.x;         // grid (16,64)
  const int nb  = (lin & 7) * 128 + (lin >> 3);         // bijective, 128/XCD
  const int bm = nb >> 4, bn = nb & 15;
  const int s0 = (nb * 5) & 15;
  const int w = t >> 6, lane = t & 63;
  const int lr = lane & 15, lg = lane >> 4;
  const int wm = (w >> 1) * 32, wn = (w & 1) * 32;
  const int g8  = lane >> 3;
  const int swz = ((lane & 7) * 16) ^ (g8 << 4);

  f32x4 acc[2][2];
#pragma unroll
  for (int i = 0; i < 2; ++i)
#pragma unroll
    for (int j = 0; j < 2; ++j) acc[i][j] = f32x4{0.f, 0.f, 0.f, 0.f};

  const size_t am = (size_t)bm * 64, bnr = (size_t)bn * 64;

  for (int kt = 0; kt < 16; ++kt) {
    const int k0 = ((kt + s0) & 15) * 64;
#pragma unroll
    for (int i = 0; i < 2; ++i) {
      const int rs = i * 32 + w * 8;
      gl_lds16((const char*)(A + (am + rs + g8) * 1024 + k0) + swz,
               (char*)lA + rs * 128);
      gl_lds16((const char*)(Bt + (bnr + rs + g8) * 1024 + k0) + swz,
               (char*)lB + rs * 128);
    }
    __syncthreads();
#pragma unroll
    for (int kk = 0; kk < 64; kk += 32) {
      bf16x8 af[2], bfr[2];
#pragma unroll
      for (int fm = 0; fm < 2; ++fm) {
        int row = wm + fm * 16 + lr;
        af[fm] = *reinterpret_cast<const bf16x8*>(
            (const char*)lA + row * 128 + ((2 * kk + lg * 16) ^ ((lr & 7) << 4)));
      }
#pragma unroll
      for (int fn = 0; fn < 2; ++fn) {
        int row = wn + fn * 16 + lr;
        bfr[fn] = *reinterpret_cast<const bf16x8*>(
            (const char*)lB + row * 128 + ((2 * kk + lg * 16) ^ ((lr & 7) << 4)));
      }
#pragma unroll
      for (int fm = 0; fm < 2; ++fm)
#pragma unroll
        for (int fn = 0; fn < 2; ++fn)
          acc[fm][fn] = __builtin_amdgcn_mfma_f32_16x16x32_bf16(
              af[fm], bfr[fn], acc[fm][fn], 0, 0, 0);
    }
    __syncthreads();
  }

#pragma unroll
  for (int fm = 0; fm < 2; ++fm)
#pragma unroll
    for (int fn = 0; fn < 2; ++fn)
#pragma unroll
      for (int r = 0; r < 4; ++r) {
        int row = bm * 64 + wm + fm * 16 + lg * 4 + r;
        int col = bn * 64 + wn + fn * 16 + lr;
        outf[(size_t)row * 1024 + col] = acc[fm][fn][r] + bias[col];
      }
}

// ---------------------------------------------------------------- attention
// R19-EXACT body (serial in-chunk reductions): q-split 64-row blocks,
// KVBLK=64, 4 blocks/CU, XCD-local mapping, sum-31 qt pairing, base-2
// softmax + defer-max.
__global__ __launch_bounds__(256, 4) void attn_kernel(
    const unsigned short* __restrict__ qb, const unsigned short* __restrict__ kb,
    const unsigned short* __restrict__ vt, unsigned short* __restrict__ attnb) {
  __shared__ __align__(16) unsigned short lK[2][64 * 64];
  __shared__ __align__(16) unsigned short lV[2][64 * 64];
  __shared__ __align__(16) unsigned short pl[4][16 * 64];
  const int bid = blockIdx.x;
  const int xcd = bid & 7, pos = bid >> 3;       // pos 0..127
  const int half = pos >> 6, idx = pos & 63;
  const int bh = xcd * 4 + half * 2 + (idx >> 5);
  const int j = idx & 31;
  const int qt = half ? (31 - j) : j;
  const int q0 = qt * 64;
  const int w = threadIdx.x >> 6, lane = threadIdx.x & 63;
  const int lr = lane & 15, lg = lane >> 4;
  const int g8  = lane >> 3;
  const int swz = ((lane & 7) * 16) ^ (g8 << 4);

  const unsigned short* Kg = kb + (size_t)bh * 2048 * 64;
  const unsigned short* Vg = vt + (size_t)bh * 64 * 2048;

  auto stage = [&](int buf, int c) {
    const size_t kv0 = (size_t)c * 64;
#pragma unroll
    for (int i = 0; i < 2; ++i) {                 // K: 64 rows
      const int rs = i * 32 + w * 8;
      gl_lds16((const char*)(Kg + (kv0 + rs + g8) * 64) + swz,
               (char*)&lK[buf][0] + rs * 128);
    }
#pragma unroll
    for (int i = 0; i < 2; ++i) {                 // V^T: 64 d-rows
      const int rs = i * 32 + w * 8;
      gl_lds16((const char*)(Vg + (size_t)(rs + g8) * 2048 + kv0) + swz,
               (char*)&lV[buf][0] + rs * 128);
    }
  };

  const int qrow = q0 + w * 16 + lr;
  bf16x8 qf[2];
#pragma unroll
  for (int kk = 0; kk < 2; ++kk)
    qf[kk] = *reinterpret_cast<const bf16x8*>(
        &qb[((size_t)bh * 2048 + qrow) * 64 + kk * 32 + lg * 8]);

  f32x4 acc[4];
#pragma unroll
  for (int i = 0; i < 4; ++i) acc[i] = f32x4{0.f, 0.f, 0.f, 0.f};
  float m = -1e30f, rsum = 0.f;

  const int nc = qt + 1;   // chunks of 64 keys
  stage(0, 0);

  for (int c = 0; c < nc; ++c) {
    const int cur = c & 1;
    __syncthreads();
    if (c + 1 < nc) stage(cur ^ 1, c + 1);

    // QK^T: S^T frags for 4 key-groups of 16
    f32x4 s[4];
#pragma unroll
    for (int i = 0; i < 4; ++i) s[i] = f32x4{0.f, 0.f, 0.f, 0.f};
#pragma unroll
    for (int nf = 0; nf < 4; ++nf) {
      const int row = nf * 16 + lr;
      bf16x8 k0 = *reinterpret_cast<const bf16x8*>(
          (const char*)&lK[cur][0] + row * 128 + ((lg * 16) ^ ((lr & 7) << 4)));
      bf16x8 k1 = *reinterpret_cast<const bf16x8*>(
          (const char*)&lK[cur][0] + row * 128 + ((64 + lg * 16) ^ ((lr & 7) << 4)));
      s[nf] = __builtin_amdgcn_mfma_f32_16x16x32_bf16(k0, qf[0], s[nf], 0, 0, 0);
      s[nf] = __builtin_amdgcn_mfma_f32_16x16x32_bf16(k1, qf[1], s[nf], 0, 0, 0);
    }

    const bool diag = (c * 64 + 63) > (q0 + w * 16);
    float ps[4][4];
    float mx = -1e30f;
    if (diag) {
#pragma unroll
      for (int nf = 0; nf < 4; ++nf)
#pragma unroll
        for (int r = 0; r < 4; ++r) {
          int key = c * 64 + nf * 16 + lg * 4 + r;
          float sv = (key <= qrow) ? s[nf][r] : -1e30f;
          ps[nf][r] = sv;
          mx = fmaxf(mx, sv);
        }
    } else {
#pragma unroll
      for (int nf = 0; nf < 4; ++nf)
#pragma unroll
        for (int r = 0; r < 4; ++r) {
          ps[nf][r] = s[nf][r];
          mx = fmaxf(mx, ps[nf][r]);
        }
    }
    mx = fmaxf(mx, __shfl_xor(mx, 16));
    mx = fmaxf(mx, __shfl_xor(mx, 32));
    if (__any(mx > m + 8.f)) {            // defer-max (T13)
      float mn = fmaxf(m, mx);
      float scl = exp2f(m - mn);
      m = mn;
      rsum *= scl;
#pragma unroll
      for (int df = 0; df < 4; ++df) acc[df] *= scl;
    }
    float ss = 0.f;
#pragma unroll
    for (int nf = 0; nf < 4; ++nf)
#pragma unroll
      for (int r = 0; r < 4; ++r) {
        float pe = exp2f(ps[nf][r] - m);
        ps[nf][r] = pe;
        ss += pe;
      }
    ss += __shfl_xor(ss, 16);
    ss += __shfl_xor(ss, 32);
    rsum += ss;

    // pack P^T -> pl (swizzled, 8B writes), then PV
#pragma unroll
    for (int nf = 0; nf < 4; ++nf) {
      uint2 pk;
      pk.x = cvtpk(ps[nf][0], ps[nf][1]);
      pk.y = cvtpk(ps[nf][2], ps[nf][3]);
      *reinterpret_cast<uint2*>(
          (char*)&pl[w][0] + lr * 128 + ((nf * 32 + lg * 8) ^ ((lr & 7) << 4))) = pk;
    }
#pragma unroll
    for (int kk = 0; kk < 2; ++kk) {
      bf16x8 pf = *reinterpret_cast<const bf16x8*>(
          (const char*)&pl[w][0] + lr * 128 + ((kk * 64 + lg * 16) ^ ((lr & 7) << 4)));
#pragma unroll
      for (int df = 0; df < 4; ++df) {
        const int row = df * 16 + lr;
        bf16x8 vf = *reinterpret_cast<const bf16x8*>(
            (const char*)&lV[cur][0] + row * 128 +
            ((kk * 64 + lg * 16) ^ ((lr & 7) << 4)));
        acc[df] = __builtin_amdgcn_mfma_f32_16x16x32_bf16(vf, pf, acc[df], 0, 0, 0);
      }
    }
  }

  const int b = bh >> 4, h = bh & 15;
  float inv = 1.f / rsum;
#pragma unroll
  for (int df = 0; df < 4; ++df) {
    ushort4 ov;
    ov.x = f2b(acc[df][0] * inv); ov.y = f2b(acc[df][1] * inv);
    ov.z = f2b(acc[df][2] * inv); ov.w = f2b(acc[df][3] * inv);
    *reinterpret_cast<ushort4*>(
        &attnb[((size_t)b * 2048 + qrow) * 1024 + h * 64 + df * 16 + lg * 4]) = ov;
  }
}

// ---------------------------------------------------------------- launch
extern "C" void kernel_launch(void* const* d_in, const int* in_sizes, int n_in,
                              void* d_out, int out_size, void* d_ws, size_t ws_size,
                              hipStream_t stream) {
  const float* x     = (const float*)d_in[0];
  const float* w_qkv = (const float*)d_in[1];
  const float* b_qkv = (const float*)d_in[2];
  const float* w_out = (const float*)d_in[3];
  const float* b_out = (const float*)d_in[4];
  float* out = (float*)d_out;
  char* ws = (char*)d_ws;

  unsigned short* xb    = (unsigned short*)(ws);               //  8.0 MB
  unsigned short* wqkvt = (unsigned short*)(ws + 8388608);     //  6.0 MB
  unsigned short* woutt = (unsigned short*)(ws + 14680064);    //  2.0 MB
  unsigned short* qb    = (unsigned short*)(ws + 16777216);    //  8.0 MB
  unsigned short* kb    = (unsigned short*)(ws + 25165824);    //  8.0 MB
  unsigned short* vt    = (unsigned short*)(ws + 33554432);    //  8.0 MB  [bh][64][2048]
  unsigned short* attnb = (unsigned short*)(ws + 41943040);    //  8.0 MB

  prep_inputs<<<4096, 256, 0, stream>>>(x, w_qkv, w_out, xb, wqkvt, woutt);
  gemm_qkv<<<dim3(24, 32), 256, 0, stream>>>(xb, wqkvt, b_qkv, qb, kb, vt);
  attn_kernel<<<1024, 256, 0, stream>>>(qb, kb, vt, attnb);
  gemm_out<<<dim3(16, 64), 256, 0, stream>>>(attnb, woutt, b_out, out);
}

// Round 24
// 112.890 us; speedup vs baseline: 1.0561x; 1.0561x over previous
//
#include <hip/hip_runtime.h>
#include <hip/hip_bf16.h>

// CausalAttention MI355X: B=2 L=2048 D=1024 H=16 HD=64  (R22-exact best)
// prep (fused converts) -> QKV GEMM (256x128, stagger, XCD swizzle,
// V^T written directly in epilogue) -> flash attention (q-split 64-row
// blocks, KVBLK=64, 4 blocks/CU, serial in-chunk reductions [R19-exact],
// XCD-local, sum-31 pairing, base-2 + defer-max) -> out GEMM (64x64, 4/CU).

using bf16x8 = __attribute__((ext_vector_type(8))) short;
using f32x4  = __attribute__((ext_vector_type(4))) float;

static __device__ __forceinline__ unsigned short f2b(float f) {
  unsigned u = __builtin_bit_cast(unsigned, f);
  unsigned r = (u + 0x7fffu + ((u >> 16) & 1u)) >> 16;
  return (unsigned short)r;
}

// pack 2 f32 -> 2 bf16 in one instr (no builtin on gfx950; T12 recipe)
static __device__ __forceinline__ unsigned cvtpk(float lo, float hi) {
  unsigned r;
  asm("v_cvt_pk_bf16_f32 %0, %1, %2" : "=v"(r) : "v"(lo), "v"(hi));
  return r;
}

// async global->LDS, 16B/lane; LDS dest wave-uniform (HW adds lane*16),
// per-lane row/swizzle on the GLOBAL address (rule 21 / m173).
static __device__ __forceinline__ void gl_lds16(const void* g, void* l) {
  __builtin_amdgcn_global_load_lds(
      (const __attribute__((address_space(1))) unsigned int*)g,
      (__attribute__((address_space(3))) unsigned int*)l, 16, 0, 0);
}

// ----------------------------------------------------- fused input prep
__global__ __launch_bounds__(256) void prep_inputs(
    const float* __restrict__ x, const float* __restrict__ w_qkv,
    const float* __restrict__ w_out, unsigned short* __restrict__ xb,
    unsigned short* __restrict__ wqkvt, unsigned short* __restrict__ woutt) {
  const int bid = blockIdx.x, t = threadIdx.x;
  if (bid < 2048) {
    int i = bid * 256 + t;
    const float4* p = reinterpret_cast<const float4*>(x) + (size_t)i * 2;
    float4 a = p[0], b = p[1];
    bf16x8 o;
    o[0] = f2b(a.x); o[1] = f2b(a.y); o[2] = f2b(a.z); o[3] = f2b(a.w);
    o[4] = f2b(b.x); o[5] = f2b(b.y); o[6] = f2b(b.z); o[7] = f2b(b.w);
    reinterpret_cast<bf16x8*>(xb)[i] = o;
  } else if (bid < 3584) {
    int idx = (bid - 2048) * 256 + t;            // N=3072, K=1024
    int n = idx % 3072, k0 = (idx / 3072) * 8;
    if (k0 < 1024) {
      bf16x8 o;
#pragma unroll
      for (int j = 0; j < 8; ++j) o[j] = f2b(w_qkv[(size_t)(k0 + j) * 3072 + n]);
      *reinterpret_cast<bf16x8*>(&wqkvt[(size_t)n * 1024 + k0]) = o;
    }
  } else {
    int idx = (bid - 3584) * 256 + t;            // N=1024, K=1024
    int n = idx % 1024, k0 = (idx / 1024) * 8;
    if (k0 < 1024) {
      bf16x8 o;
#pragma unroll
      for (int j = 0; j < 8; ++j) o[j] = f2b(w_out[(size_t)(k0 + j) * 1024 + n]);
      *reinterpret_cast<bf16x8*>(&woutt[(size_t)n * 1024 + k0]) = o;
    }
  }
}

// ------------------------------------------------ QKV GEMM: 256x128, stagger
// V is written TRANSPOSED directly: thread's acc r=0..3 are 4 consecutive
// L-rows for a fixed d -> one aligned ushort4 store into vt[bh][d][l..l+3].
__global__ __launch_bounds__(512) void gemm_qkv(
    const unsigned short* __restrict__ A,
    const unsigned short* __restrict__ Bt,
    const float* __restrict__ bias,
    unsigned short* __restrict__ qb, unsigned short* __restrict__ kb,
    unsigned short* __restrict__ vt) {
  __shared__ __align__(16) unsigned short lA[256 * 64];
  __shared__ __align__(16) unsigned short lB[128 * 64];
  const int t = threadIdx.x;
  const int lin = blockIdx.y * 24 + blockIdx.x;          // grid (24,16)
  const int nb  = (lin & 7) * 48 + (lin >> 3);
  const int bm = nb / 24, bn = nb % 24;
  const int s0 = (nb * 5) & 15;
  const int w = t >> 6, lane = t & 63;
  const int lr = lane & 15, lg = lane >> 4;
  const int wm = (w >> 1) * 64, wn = (w & 1) * 64;
  const int g8  = lane >> 3;
  const int swz = ((lane & 7) * 16) ^ (g8 << 4);

  f32x4 acc[4][4];
#pragma unroll
  for (int i = 0; i < 4; ++i)
#pragma unroll
    for (int j = 0; j < 4; ++j) acc[i][j] = f32x4{0.f, 0.f, 0.f, 0.f};

  const size_t am = (size_t)bm * 256, bnr = (size_t)bn * 128;

  for (int kt = 0; kt < 16; ++kt) {
    const int k0 = ((kt + s0) & 15) * 64;
#pragma unroll
    for (int i = 0; i < 4; ++i) {                 // A: 256 rows
      const int rs = i * 64 + w * 8;
      gl_lds16((const char*)(A + (am + rs + g8) * 1024 + k0) + swz,
               (char*)lA + rs * 128);
    }
#pragma unroll
    for (int i = 0; i < 2; ++i) {                 // B: 128 rows
      const int rs = i * 64 + w * 8;
      gl_lds16((const char*)(Bt + (bnr + rs + g8) * 1024 + k0) + swz,
               (char*)lB + rs * 128);
    }
    __syncthreads();
#pragma unroll
    for (int kk = 0; kk < 64; kk += 32) {
      bf16x8 af[4], bfr[4];
#pragma unroll
      for (int fm = 0; fm < 4; ++fm) {
        int row = wm + fm * 16 + lr;
        af[fm] = *reinterpret_cast<const bf16x8*>(
            (const char*)lA + row * 128 + ((2 * kk + lg * 16) ^ ((lr & 7) << 4)));
      }
#pragma unroll
      for (int fn = 0; fn < 4; ++fn) {
        int row = wn + fn * 16 + lr;
        bfr[fn] = *reinterpret_cast<const bf16x8*>(
            (const char*)lB + row * 128 + ((2 * kk + lg * 16) ^ ((lr & 7) << 4)));
      }
#pragma unroll
      for (int fm = 0; fm < 4; ++fm)
#pragma unroll
        for (int fn = 0; fn < 4; ++fn)
          acc[fm][fn] = __builtin_amdgcn_mfma_f32_16x16x32_bf16(
              af[fm], bfr[fn], acc[fm][fn], 0, 0, 0);
    }
    __syncthreads();
  }

#pragma unroll
  for (int fm = 0; fm < 4; ++fm) {
#pragma unroll
    for (int fn = 0; fn < 4; ++fn) {
      const int row0 = bm * 256 + wm + fm * 16 + lg * 4;
      const int col  = bn * 128 + wn + fn * 16 + lr;
      const float bc = bias[col];
      float v4[4];
#pragma unroll
      for (int r = 0; r < 4; ++r) v4[r] = acc[fm][fn][r] + bc;
      const int bb = row0 >> 11, l0 = row0 & 2047;
      const int which = col >> 10, hn = col & 1023;
      const int h = hn >> 6, d = hn & 63;
      const int bh = bb * 16 + h;
      if (which == 0) {
#pragma unroll
        for (int r = 0; r < 4; ++r)
          qb[((size_t)bh * 2048 + l0 + r) * 64 + d] = f2b(v4[r] * 0.180336879f);
      } else if (which == 1) {
#pragma unroll
        for (int r = 0; r < 4; ++r)
          kb[((size_t)bh * 2048 + l0 + r) * 64 + d] = f2b(v4[r]);
      } else {
        ushort4 o;
        o.x = f2b(v4[0]); o.y = f2b(v4[1]); o.z = f2b(v4[2]); o.w = f2b(v4[3]);
        *reinterpret_cast<ushort4*>(&vt[((size_t)bh * 64 + d) * 2048 + l0]) = o;
      }
    }
  }
}

// ---------------------------------------------------------------- out GEMM
// 64x64 tile -> grid 1024 = 4 blocks/CU (de-convoy lever). Wave tile 32x32.
__global__ __launch_bounds__(256) void gemm_out(
    const unsigned short* __restrict__ A,
    const unsigned short* __restrict__ Bt,
    const float* __restrict__ bias, float* __restrict__ outf) {
  __shared__ __align__(16) unsigned short lA[64 * 64];
  __shared__ __align__(16) unsigned short lB[64 * 64];
  const int t = threadIdx.x;
  const int lin = blockIdx.y * 16 + blockIdx.x;         // grid (16,64)
  const int nb  = (lin & 7) * 128 + (lin >> 3);         // bijective, 128/XCD
  const int bm = nb >> 4, bn = nb & 15;
  const int s0 = (nb * 5) & 15;
  const int w = t >> 6, lane = t & 63;
  const int lr = lane & 15, lg = lane >> 4;
  const int wm = (w >> 1) * 32, wn = (w & 1) * 32;
  const int g8  = lane >> 3;
  const int swz = ((lane & 7) * 16) ^ (g8 << 4);

  f32x4 acc[2][2];
#pragma unroll
  for (int i = 0; i < 2; ++i)
#pragma unroll
    for (int j = 0; j < 2; ++j) acc[i][j] = f32x4{0.f, 0.f, 0.f, 0.f};

  const size_t am = (size_t)bm * 64, bnr = (size_t)bn * 64;

  for (int kt = 0; kt < 16; ++kt) {
    const int k0 = ((kt + s0) & 15) * 64;
#pragma unroll
    for (int i = 0; i < 2; ++i) {                 // A: 64 rows
      const int rs = i * 32 + w * 8;
      gl_lds16((const char*)(A + (am + rs + g8) * 1024 + k0) + swz,
               (char*)lA + rs * 128);
    }
#pragma unroll
    for (int i = 0; i < 2; ++i) {                 // B: 64 rows
      const int rs = i * 32 + w * 8;
      gl_lds16((const char*)(Bt + (bnr + rs + g8) * 1024 + k0) + swz,
               (char*)lB + rs * 128);
    }
    __syncthreads();
#pragma unroll
    for (int kk = 0; kk < 64; kk += 32) {
      bf16x8 af[2], bfr[2];
#pragma unroll
      for (int fm = 0; fm < 2; ++fm) {
        int row = wm + fm * 16 + lr;
        af[fm] = *reinterpret_cast<const bf16x8*>(
            (const char*)lA + row * 128 + ((2 * kk + lg * 16) ^ ((lr & 7) << 4)));
      }
#pragma unroll
      for (int fn = 0; fn < 2; ++fn) {
        int row = wn + fn * 16 + lr;
        bfr[fn] = *reinterpret_cast<const bf16x8*>(
            (const char*)lB + row * 128 + ((2 * kk + lg * 16) ^ ((lr & 7) << 4)));
      }
#pragma unroll
      for (int fm = 0; fm < 2; ++fm)
#pragma unroll
        for (int fn = 0; fn < 2; ++fn)
          acc[fm][fn] = __builtin_amdgcn_mfma_f32_16x16x32_bf16(
              af[fm], bfr[fn], acc[fm][fn], 0, 0, 0);
    }
    __syncthreads();
  }

#pragma unroll
  for (int fm = 0; fm < 2; ++fm)
#pragma unroll
    for (int fn = 0; fn < 2; ++fn)
#pragma unroll
      for (int r = 0; r < 4; ++r) {
        int row = bm * 64 + wm + fm * 16 + lg * 4 + r;
        int col = bn * 64 + wn + fn * 16 + lr;
        outf[(size_t)row * 1024 + col] = acc[fm][fn][r] + bias[col];
      }
}

// ---------------------------------------------------------------- attention
// R19-EXACT body (serial in-chunk reductions): q-split 64-row blocks,
// KVBLK=64, 4 blocks/CU, XCD-local mapping, sum-31 qt pairing, base-2
// softmax + defer-max.
__global__ __launch_bounds__(256, 4) void attn_kernel(
    const unsigned short* __restrict__ qb, const unsigned short* __restrict__ kb,
    const unsigned short* __restrict__ vt, unsigned short* __restrict__ attnb) {
  __shared__ __align__(16) unsigned short lK[2][64 * 64];
  __shared__ __align__(16) unsigned short lV[2][64 * 64];
  __shared__ __align__(16) unsigned short pl[4][16 * 64];
  const int bid = blockIdx.x;
  const int xcd = bid & 7, pos = bid >> 3;       // pos 0..127
  const int half = pos >> 6, idx = pos & 63;
  const int bh = xcd * 4 + half * 2 + (idx >> 5);
  const int j = idx & 31;
  const int qt = half ? (31 - j) : j;
  const int q0 = qt * 64;
  const int w = threadIdx.x >> 6, lane = threadIdx.x & 63;
  const int lr = lane & 15, lg = lane >> 4;
  const int g8  = lane >> 3;
  const int swz = ((lane & 7) * 16) ^ (g8 << 4);

  const unsigned short* Kg = kb + (size_t)bh * 2048 * 64;
  const unsigned short* Vg = vt + (size_t)bh * 64 * 2048;

  auto stage = [&](int buf, int c) {
    const size_t kv0 = (size_t)c * 64;
#pragma unroll
    for (int i = 0; i < 2; ++i) {                 // K: 64 rows
      const int rs = i * 32 + w * 8;
      gl_lds16((const char*)(Kg + (kv0 + rs + g8) * 64) + swz,
               (char*)&lK[buf][0] + rs * 128);
    }
#pragma unroll
    for (int i = 0; i < 2; ++i) {                 // V^T: 64 d-rows
      const int rs = i * 32 + w * 8;
      gl_lds16((const char*)(Vg + (size_t)(rs + g8) * 2048 + kv0) + swz,
               (char*)&lV[buf][0] + rs * 128);
    }
  };

  const int qrow = q0 + w * 16 + lr;
  bf16x8 qf[2];
#pragma unroll
  for (int kk = 0; kk < 2; ++kk)
    qf[kk] = *reinterpret_cast<const bf16x8*>(
        &qb[((size_t)bh * 2048 + qrow) * 64 + kk * 32 + lg * 8]);

  f32x4 acc[4];
#pragma unroll
  for (int i = 0; i < 4; ++i) acc[i] = f32x4{0.f, 0.f, 0.f, 0.f};
  float m = -1e30f, rsum = 0.f;

  const int nc = qt + 1;   // chunks of 64 keys
  stage(0, 0);

  for (int c = 0; c < nc; ++c) {
    const int cur = c & 1;
    __syncthreads();
    if (c + 1 < nc) stage(cur ^ 1, c + 1);

    // QK^T: S^T frags for 4 key-groups of 16
    f32x4 s[4];
#pragma unroll
    for (int i = 0; i < 4; ++i) s[i] = f32x4{0.f, 0.f, 0.f, 0.f};
#pragma unroll
    for (int nf = 0; nf < 4; ++nf) {
      const int row = nf * 16 + lr;
      bf16x8 k0 = *reinterpret_cast<const bf16x8*>(
          (const char*)&lK[cur][0] + row * 128 + ((lg * 16) ^ ((lr & 7) << 4)));
      bf16x8 k1 = *reinterpret_cast<const bf16x8*>(
          (const char*)&lK[cur][0] + row * 128 + ((64 + lg * 16) ^ ((lr & 7) << 4)));
      s[nf] = __builtin_amdgcn_mfma_f32_16x16x32_bf16(k0, qf[0], s[nf], 0, 0, 0);
      s[nf] = __builtin_amdgcn_mfma_f32_16x16x32_bf16(k1, qf[1], s[nf], 0, 0, 0);
    }

    const bool diag = (c * 64 + 63) > (q0 + w * 16);
    float ps[4][4];
    float mx = -1e30f;
    if (diag) {
#pragma unroll
      for (int nf = 0; nf < 4; ++nf)
#pragma unroll
        for (int r = 0; r < 4; ++r) {
          int key = c * 64 + nf * 16 + lg * 4 + r;
          float sv = (key <= qrow) ? s[nf][r] : -1e30f;
          ps[nf][r] = sv;
          mx = fmaxf(mx, sv);
        }
    } else {
#pragma unroll
      for (int nf = 0; nf < 4; ++nf)
#pragma unroll
        for (int r = 0; r < 4; ++r) {
          ps[nf][r] = s[nf][r];
          mx = fmaxf(mx, ps[nf][r]);
        }
    }
    mx = fmaxf(mx, __shfl_xor(mx, 16));
    mx = fmaxf(mx, __shfl_xor(mx, 32));
    if (__any(mx > m + 8.f)) {            // defer-max (T13)
      float mn = fmaxf(m, mx);
      float scl = exp2f(m - mn);
      m = mn;
      rsum *= scl;
#pragma unroll
      for (int df = 0; df < 4; ++df) acc[df] *= scl;
    }
    float ss = 0.f;
#pragma unroll
    for (int nf = 0; nf < 4; ++nf)
#pragma unroll
      for (int r = 0; r < 4; ++r) {
        float pe = exp2f(ps[nf][r] - m);
        ps[nf][r] = pe;
        ss += pe;
      }
    ss += __shfl_xor(ss, 16);
    ss += __shfl_xor(ss, 32);
    rsum += ss;

    // pack P^T -> pl (swizzled, 8B writes), then PV
#pragma unroll
    for (int nf = 0; nf < 4; ++nf) {
      uint2 pk;
      pk.x = cvtpk(ps[nf][0], ps[nf][1]);
      pk.y = cvtpk(ps[nf][2], ps[nf][3]);
      *reinterpret_cast<uint2*>(
          (char*)&pl[w][0] + lr * 128 + ((nf * 32 + lg * 8) ^ ((lr & 7) << 4))) = pk;
    }
#pragma unroll
    for (int kk = 0; kk < 2; ++kk) {
      bf16x8 pf = *reinterpret_cast<const bf16x8*>(
          (const char*)&pl[w][0] + lr * 128 + ((kk * 64 + lg * 16) ^ ((lr & 7) << 4)));
#pragma unroll
      for (int df = 0; df < 4; ++df) {
        const int row = df * 16 + lr;
        bf16x8 vf = *reinterpret_cast<const bf16x8*>(
            (const char*)&lV[cur][0] + row * 128 +
            ((kk * 64 + lg * 16) ^ ((lr & 7) << 4)));
        acc[df] = __builtin_amdgcn_mfma_f32_16x16x32_bf16(vf, pf, acc[df], 0, 0, 0);
      }
    }
  }

  const int b = bh >> 4, h = bh & 15;
  float inv = 1.f / rsum;
#pragma unroll
  for (int df = 0; df < 4; ++df) {
    ushort4 ov;
    ov.x = f2b(acc[df][0] * inv); ov.y = f2b(acc[df][1] * inv);
    ov.z = f2b(acc[df][2] * inv); ov.w = f2b(acc[df][3] * inv);
    *reinterpret_cast<ushort4*>(
        &attnb[((size_t)b * 2048 + qrow) * 1024 + h * 64 + df * 16 + lg * 4]) = ov;
  }
}

// ---------------------------------------------------------------- launch
extern "C" void kernel_launch(void* const* d_in, const int* in_sizes, int n_in,
                              void* d_out, int out_size, void* d_ws, size_t ws_size,
                              hipStream_t stream) {
  const float* x     = (const float*)d_in[0];
  const float* w_qkv = (const float*)d_in[1];
  const float* b_qkv = (const float*)d_in[2];
  const float* w_out = (const float*)d_in[3];
  const float* b_out = (const float*)d_in[4];
  float* out = (float*)d_out;
  char* ws = (char*)d_ws;

  unsigned short* xb    = (unsigned short*)(ws);               //  8.0 MB
  unsigned short* wqkvt = (unsigned short*)(ws + 8388608);     //  6.0 MB
  unsigned short* woutt = (unsigned short*)(ws + 14680064);    //  2.0 MB
  unsigned short* qb    = (unsigned short*)(ws + 16777216);    //  8.0 MB
  unsigned short* kb    = (unsigned short*)(ws + 25165824);    //  8.0 MB
  unsigned short* vt    = (unsigned short*)(ws + 33554432);    //  8.0 MB  [bh][64][2048]
  unsigned short* attnb = (unsigned short*)(ws + 41943040);    //  8.0 MB

  prep_inputs<<<4096, 256, 0, stream>>>(x, w_qkv, w_out, xb, wqkvt, woutt);
  gemm_qkv<<<dim3(24, 16), 512, 0, stream>>>(xb, wqkvt, b_qkv, qb, kb, vt);
  attn_kernel<<<1024, 256, 0, stream>>>(qb, kb, vt, attnb);
  gemm_out<<<dim3(16, 64), 256, 0, stream>>>(attnb, woutt, b_out, out);
}